// Round 1
// 819.796 us; speedup vs baseline: 1.0450x; 1.0450x over previous
//
#include <hip/hip_runtime.h>

// ---------------------------------------------------------------------------
// H2Q knot kernel: embed -> 8 doubling quaternion expansion steps ->
// 6 quaternion-linear+normalize layers -> vocab head (+ stability loss).
// R6: port layer + head GEMMs to a 256x256 8-wave schedule with
//   T2  LDS XOR swizzle (read byte ^ ((row&6)<<3), inverse-swizzled source)
//   T3/T4 2-phase-per-K-tile interleave, ring-of-4 LDS buffers (128 KiB),
//        counted s_waitcnt vmcnt(8) at tile boundaries (never 0 in loop)
//   T5  s_setprio(1) around each 16-MFMA cluster
// Expansion steps (small K) stay on the old 128x128 2-barrier kernel.
// ---------------------------------------------------------------------------

typedef _Float16 f16x8 __attribute__((ext_vector_type(8)));
typedef float    f32x4 __attribute__((ext_vector_type(4)));

#define GL2LDS16(gp, lp) __builtin_amdgcn_global_load_lds(                     \
    (const __attribute__((address_space(1))) void*)(gp),                       \
    (__attribute__((address_space(3))) void*)(lp), 16, 0, 0)

__device__ __forceinline__ unsigned short f2h(float f) {
  union { _Float16 h; unsigned short u; } c;
  c.h = (_Float16)f;                       // RNE
  return c.u;
}
__device__ __forceinline__ float h2f(unsigned short u) {
  union { unsigned short u; _Float16 h; } c;
  c.u = u;
  return (float)c.h;
}

// ---------------------------------------------------------------------------
// Weight expansion: quaternion weights [4][cq][cq] -> real fp16 matrix
// E[n][k], n=4o+a (out), k=4i+b (in), rows >= 4cq zero-padded.
// ---------------------------------------------------------------------------
__global__ __launch_bounds__(256) void expand_ham(
    const float* __restrict__ w, unsigned short* __restrict__ out,
    int cq, int kbits, int total) {
  int id = blockIdx.x * 256 + threadIdx.x;
  if (id >= total) return;
  const int K = 1 << kbits;
  const int n = id >> kbits;
  const int k = id & (K - 1);
  float val = 0.f;
  if (n < 4 * cq) {
    const int o = n >> 2, a = n & 3, i = k >> 2, b = k & 3;
    const int   comp[4][4] = {{0,1,2,3},{1,0,3,2},{2,3,0,1},{3,2,1,0}};
    const float sgn [4][4] = {{1.f,-1.f,-1.f,-1.f},{1.f,1.f,1.f,-1.f},
                              {1.f,-1.f,1.f,1.f},{1.f,1.f,-1.f,1.f}};
    val = sgn[a][b] * w[comp[a][b] * cq * cq + o * cq + i];
  }
  out[id] = f2h(val);
}

__global__ __launch_bounds__(256) void conv_head(
    const float* __restrict__ wh, unsigned short* __restrict__ out) {
  int id = blockIdx.x * 256 + threadIdx.x;   // 384*1024 threads
  int v = id >> 10, k = id & 1023;
  out[id] = f2h(v < 257 ? wh[v * 1024 + k] : 0.f);
}

// ---------------------------------------------------------------------------
// Embed + expansion steps 0..3 (cq=1,2,4,8), one token per thread.
// ---------------------------------------------------------------------------
template <int CQ>
__device__ __forceinline__ void exp_step(float (&q)[16][4],
                                         const float* __restrict__ w) {
  float d[CQ][4];
#pragma unroll
  for (int o = 0; o < CQ; o++) {
    float pr = 0.f, pi = 0.f, pj = 0.f, pk = 0.f;
#pragma unroll
    for (int i = 0; i < CQ; i++) {
      const float wr = w[0 * CQ * CQ + o * CQ + i];
      const float wi = w[1 * CQ * CQ + o * CQ + i];
      const float wj = w[2 * CQ * CQ + o * CQ + i];
      const float wk = w[3 * CQ * CQ + o * CQ + i];
      const float qr = q[i][0], qi = q[i][1], qj = q[i][2], qk = q[i][3];
      pr += wr * qr - wi * qi - wj * qj - wk * qk;
      pi += wi * qr + wr * qi + wk * qj - wj * qk;
      pj += wj * qr - wk * qi + wr * qj + wi * qk;
      pk += wk * qr + wj * qi - wi * qj + wr * qk;
    }
    d[o][0] = tanhf(pr); d[o][1] = tanhf(pi);
    d[o][2] = tanhf(pj); d[o][3] = tanhf(pk);
  }
#pragma unroll
  for (int o = 0; o < CQ; o++)
#pragma unroll
    for (int a = 0; a < 4; a++) {
      const float dd = d[o][a], qq = q[o][a];
      q[o][a]      = qq + dd;
      q[CQ + o][a] = qq - dd;
    }
}

__global__ __launch_bounds__(256) void embed_expand(
    const int* __restrict__ x, const float* __restrict__ emb,
    const float* __restrict__ w0, const float* __restrict__ w1,
    const float* __restrict__ w2, const float* __restrict__ w3,
    unsigned short* __restrict__ out) {
  const int t = blockIdx.x * 256 + threadIdx.x;  // 32768 tokens
  float q[16][4];
  const int v = x[t];
  const float4 e = *(const float4*)(emb + v * 4);
  q[0][0] = e.x; q[0][1] = e.y; q[0][2] = e.z; q[0][3] = e.w;
  exp_step<1>(q, w0);
  exp_step<2>(q, w1);
  exp_step<4>(q, w2);
  exp_step<8>(q, w3);
  ushort4* o4 = (ushort4*)(out + (size_t)t * 64);
#pragma unroll
  for (int c = 0; c < 16; c++) {
    ushort4 u;
    u.x = f2h(q[c][0]); u.y = f2h(q[c][1]);
    u.z = f2h(q[c][2]); u.w = f2h(q[c][3]);
    o4[c] = u;
  }
}

// ---------------------------------------------------------------------------
// Old 128x128 fused GEMM, kept only for expansion steps (EPI 0).
// ---------------------------------------------------------------------------
template <int EPI>
__global__ __launch_bounds__(256) void gemm_epi(
    const unsigned short* __restrict__ W,
    const unsigned short* __restrict__ Act,
    unsigned short* __restrict__ OutB, float* __restrict__ OutF,
    int K, int Nreal, int ldout) {
  __shared__ unsigned short WtL[128 * 32];
  __shared__ unsigned short WtH[128 * 32];
  __shared__ unsigned short AtL[128 * 32];
  __shared__ unsigned short AtH[128 * 32];

  const int tid  = threadIdx.x;
  const int wave = tid >> 6;
  const int lane = tid & 63;
  const int l15  = lane & 15;
  const int quad = lane >> 4;

  const int Gx = gridDim.x;
  const int L  = blockIdx.y * Gx + blockIdx.x;
  const int j  = L & 7;
  const int s  = L >> 3;
  const int nblock = (s % Gx) * 128;               // n (output feature)
  const int mblock = (32 * j + s / Gx) * 128;      // token
  const int wn = (wave & 1) * 64;
  const int wm = (wave >> 1) * 64;

  f32x4 acc[4][4];
  const f32x4 zero = {0.f, 0.f, 0.f, 0.f};
#pragma unroll
  for (int a = 0; a < 4; a++)
#pragma unroll
    for (int b = 0; b < 4; b++) acc[a][b] = zero;

  const int row0 = tid >> 2;
  const int sub  = tid & 3;
  const unsigned short* gW0 = W   + (size_t)(nblock + row0)      * K + sub * 8;
  const unsigned short* gW1 = W   + (size_t)(nblock + row0 + 64) * K + sub * 8;
  const unsigned short* gA0 = Act + (size_t)(mblock + row0)      * K + sub * 8;
  const unsigned short* gA1 = Act + (size_t)(mblock + row0 + 64) * K + sub * 8;
  unsigned short* lWL0 = &WtL[wave * 512];
  unsigned short* lWL1 = &WtL[2048 + wave * 512];
  unsigned short* lWH0 = &WtH[wave * 512];
  unsigned short* lWH1 = &WtH[2048 + wave * 512];
  unsigned short* lAL0 = &AtL[wave * 512];
  unsigned short* lAL1 = &AtL[2048 + wave * 512];
  unsigned short* lAH0 = &AtH[wave * 512];
  unsigned short* lAH1 = &AtH[2048 + wave * 512];

  for (int kb = 0; kb < K; kb += 64) {
    GL2LDS16(gW0 + kb,      lWL0);
    GL2LDS16(gW1 + kb,      lWL1);
    GL2LDS16(gW0 + kb + 32, lWH0);
    GL2LDS16(gW1 + kb + 32, lWH1);
    GL2LDS16(gA0 + kb,      lAL0);
    GL2LDS16(gA1 + kb,      lAL1);
    GL2LDS16(gA0 + kb + 32, lAH0);
    GL2LDS16(gA1 + kb + 32, lAH1);
    __syncthreads();

    {
      f16x8 afr[4], bfr[4];
#pragma unroll
      for (int tn = 0; tn < 4; tn++)
        afr[tn] = *(const f16x8*)&WtL[(wn + tn * 16 + l15) * 32 + quad * 8];
#pragma unroll
      for (int tm = 0; tm < 4; tm++)
        bfr[tm] = *(const f16x8*)&AtL[(wm + tm * 16 + l15) * 32 + quad * 8];
#pragma unroll
      for (int tn = 0; tn < 4; tn++)
#pragma unroll
        for (int tm = 0; tm < 4; tm++)
          acc[tn][tm] = __builtin_amdgcn_mfma_f32_16x16x32_f16(
              afr[tn], bfr[tm], acc[tn][tm], 0, 0, 0);
    }
    {
      f16x8 afr[4], bfr[4];
#pragma unroll
      for (int tn = 0; tn < 4; tn++)
        afr[tn] = *(const f16x8*)&WtH[(wn + tn * 16 + l15) * 32 + quad * 8];
#pragma unroll
      for (int tm = 0; tm < 4; tm++)
        bfr[tm] = *(const f16x8*)&AtH[(wm + tm * 16 + l15) * 32 + quad * 8];
#pragma unroll
      for (int tn = 0; tn < 4; tn++)
#pragma unroll
        for (int tm = 0; tm < 4; tm++)
          acc[tn][tm] = __builtin_amdgcn_mfma_f32_16x16x32_f16(
              afr[tn], bfr[tm], acc[tn][tm], 0, 0, 0);
    }
    __syncthreads();
  }

  // EPI == 0 : expansion step epilogue
#pragma unroll
  for (int tn = 0; tn < 4; tn++) {
    const int n = nblock + wn + tn * 16 + quad * 4;
    if (n < Nreal) {
#pragma unroll
      for (int tm = 0; tm < 4; tm++) {
        const int token = mblock + wm + tm * 16 + l15;
        const f32x4 v = acc[tn][tm];
        const unsigned short* ip = Act + (size_t)token * K + n;
        const float i0 = h2f(ip[0]), i1 = h2f(ip[1]);
        const float i2 = h2f(ip[2]), i3 = h2f(ip[3]);
        const float d0 = tanhf(v[0]), d1 = tanhf(v[1]);
        const float d2 = tanhf(v[2]), d3 = tanhf(v[3]);
        ushort4 up, um;
        up.x = f2h(i0 + d0); up.y = f2h(i1 + d1);
        up.z = f2h(i2 + d2); up.w = f2h(i3 + d3);
        um.x = f2h(i0 - d0); um.y = f2h(i1 - d1);
        um.z = f2h(i2 - d2); um.w = f2h(i3 - d3);
        *(ushort4*)&OutB[(size_t)token * ldout + n] = up;
        *(ushort4*)&OutB[(size_t)token * ldout + Nreal + n] = um;
      }
    }
  }
}

// ---------------------------------------------------------------------------
// New 256x256 8-wave scheduled GEMM (layers + head).
// D[n][token] = sum_k W[n][k] * Act[token][k], both fp16 k-contiguous.
// BK=32, ring of 4 LDS buffers (4 x (A 16KB + B 16KB) = 128 KiB), staging
// 3 K-tiles ahead via global_load_lds w16 (4 loads/thread/tile, 2 per phase).
// Per K-tile: 2 phases x 16 MFMA; raw s_barrier + lgkmcnt(0)+sched_barrier
// before MFMA (rule: hipcc hoists reg-only MFMA past asm lgkmcnt), setprio(1)
// around the MFMA cluster. Tile boundary: s_waitcnt vmcnt(8) (tiles kt+2,kt+3
// in flight) -> counted, never drained to 0 in the main loop.
// T2 swizzle: LDS read byte ^= ((row&6)<<3); inverse applied to the per-lane
// GLOBAL source k-slot (linear LDS dest, pre-swizzled source — both-sides).
// C/D: col=token=lane&15, row=n=(lane>>4)*4+reg (lane f32x4 = one quaternion).
// EPI: 1 = qnormalize -> fp16 [token][1024]
//      2 = EPI1 + stability loss
//      3 = head, fp32 store to OutF[token*257+n], n<257 (W rows clamped <NW)
// ---------------------------------------------------------------------------
template <int EPI>
__global__ __launch_bounds__(512, 2) void gemm8p(
    const unsigned short* __restrict__ W,
    const unsigned short* __restrict__ Act,
    unsigned short* __restrict__ OutB, float* __restrict__ OutF,
    int K, int NW) {
  __shared__ unsigned short S[65536];   // 128 KiB: buf b at b*16384 (hw units)
  __shared__ float lsum[8];

  const int tid  = threadIdx.x;
  const int wave = tid >> 6;
  const int lane = tid & 63;
  const int l15  = lane & 15;
  const int quad = lane >> 4;
  const int wr   = wave >> 2;          // 0..1  n half (128 rows)
  const int wc   = wave & 3;           // 0..3  token quarter (64 cols)

  // XCD swizzle: xcd j = L%8 owns token-tiles [j*Gy/8, (j+1)*Gy/8), n fastest
  const int Gx = gridDim.x;
  const int L  = blockIdx.y * Gx + blockIdx.x;
  const int j  = L & 7;
  const int s  = L >> 3;
  const int mtile = j * (gridDim.y >> 3) + s / Gx;
  const int ntile = s % Gx;
  const int nblock = ntile * 256;
  const int mblock = mtile * 256;

  const int NT = K >> 5;               // K-tiles of 32

  f32x4 acc[8][4];
  const f32x4 zero = {0.f, 0.f, 0.f, 0.f};
#pragma unroll
  for (int a = 0; a < 8; a++)
#pragma unroll
    for (int b = 0; b < 4; b++) acc[a][b] = zero;

  // Staging: chunk c covers tile rows c*128+(tid>>2), slot tid&3 (16B of 64B
  // row). Source k-slot is inverse-swizzled: sl = (tid&3) ^ ((row&6)>>1).
  const int rA = tid >> 2;
  const int sl = (tid & 3) ^ ((tid >> 3) & 3);
  const int w0r = nblock + rA;
  const int w1r = nblock + 128 + rA;
  const int cw0 = w0r < NW ? w0r : NW - 1;   // clamp (head: rows>=384 read
  const int cw1 = w1r < NW ? w1r : NW - 1;   // zero-padded row; masked store)
  const unsigned short* sW0 = W   + (size_t)cw0 * K + sl * 8;
  const unsigned short* sW1 = W   + (size_t)cw1 * K + sl * 8;
  const unsigned short* sA0 = Act + (size_t)(mblock + rA)       * K + sl * 8;
  const unsigned short* sA1 = Act + (size_t)(mblock + 128 + rA) * K + sl * 8;

  // Read-side swizzle: rows are X*16+l15 -> row&6 == l15&6, constant per lane
  const int swz = (quad * 8) ^ ((l15 & 6) << 2);   // halfword offset XOR

  // prologue: stage tiles 0..2 fully
  for (int t = 0; t < 3 && t < NT; ++t) {
    const int kb = t * 32;
    unsigned short* d = S + t * 16384 + tid * 8;
    GL2LDS16(sW0 + kb, d);
    GL2LDS16(sA0 + kb, d + 8192);
    GL2LDS16(sW1 + kb, d + 4096);
    GL2LDS16(sA1 + kb, d + 12288);
  }
  if (NT >= 3)      asm volatile("s_waitcnt vmcnt(8)" ::: "memory");
  else if (NT == 2) asm volatile("s_waitcnt vmcnt(4)" ::: "memory");
  else              asm volatile("s_waitcnt vmcnt(0)" ::: "memory");
  __builtin_amdgcn_s_barrier();

  for (int kt = 0; kt < NT; ++kt) {
    const unsigned short* SA = S + (kt & 3) * 16384;
    const unsigned short* SB = SA + 8192;
    const int  nxt = (kt + 3) & 3;
    const bool pf  = (kt + 3) < NT;
    const int  kb  = (kt + 3) * 32;
    unsigned short* d = S + nxt * 16384 + tid * 8;

    f16x8 af[4], bf[4];
    // ---- phase A: n-frags 0..3 --------------------------------------------
#pragma unroll
    for (int t4 = 0; t4 < 4; t4++)
      af[t4] = *(const f16x8*)(SA + (wr * 128 + t4 * 16 + l15) * 32 + swz);
#pragma unroll
    for (int t4 = 0; t4 < 4; t4++)
      bf[t4] = *(const f16x8*)(SB + (wc * 64 + t4 * 16 + l15) * 32 + swz);
    if (pf) { GL2LDS16(sW0 + kb, d); GL2LDS16(sA0 + kb, d + 8192); }
    __builtin_amdgcn_s_barrier();
    asm volatile("s_waitcnt lgkmcnt(0)" ::: "memory");
    __builtin_amdgcn_sched_barrier(0);
    __builtin_amdgcn_s_setprio(1);
#pragma unroll
    for (int tn = 0; tn < 4; tn++)
#pragma unroll
      for (int tm = 0; tm < 4; tm++)
        acc[tn][tm] = __builtin_amdgcn_mfma_f32_16x16x32_f16(
            af[tn], bf[tm], acc[tn][tm], 0, 0, 0);
    __builtin_amdgcn_s_setprio(0);
    __builtin_amdgcn_s_barrier();
    // ---- phase B: n-frags 4..7 (bf reused) --------------------------------
#pragma unroll
    for (int t4 = 0; t4 < 4; t4++)
      af[t4] = *(const f16x8*)(SA + (wr * 128 + 64 + t4 * 16 + l15) * 32 + swz);
    if (pf) { GL2LDS16(sW1 + kb, d + 4096); GL2LDS16(sA1 + kb, d + 12288); }
    __builtin_amdgcn_s_barrier();
    asm volatile("s_waitcnt lgkmcnt(0)" ::: "memory");
    __builtin_amdgcn_sched_barrier(0);
    __builtin_amdgcn_s_setprio(1);
#pragma unroll
    for (int tn = 0; tn < 4; tn++)
#pragma unroll
      for (int tm = 0; tm < 4; tm++)
        acc[4 + tn][tm] = __builtin_amdgcn_mfma_f32_16x16x32_f16(
            af[tn], bf[tm], acc[4 + tn][tm], 0, 0, 0);
    __builtin_amdgcn_s_setprio(0);
    // ---- tile boundary: counted vmcnt (tile kt+1 landed; kt+2/kt+3 fly) ---
    if (kt < NT - 1) {
      if (kt + 3 < NT)       asm volatile("s_waitcnt vmcnt(8)" ::: "memory");
      else if (kt + 3 == NT) asm volatile("s_waitcnt vmcnt(4)" ::: "memory");
      else                   asm volatile("s_waitcnt vmcnt(0)" ::: "memory");
      __builtin_amdgcn_s_barrier();
    }
  }

  if constexpr (EPI == 1 || EPI == 2) {
    float loss = 0.f;
#pragma unroll
    for (int tn = 0; tn < 8; tn++) {
      const int n = nblock + wr * 128 + tn * 16 + quad * 4;
#pragma unroll
      for (int tm = 0; tm < 4; tm++) {
        const int token = mblock + wc * 64 + tm * 16 + l15;
        const f32x4 v = acc[tn][tm];
        const float nrm =
            sqrtf(v[0] * v[0] + v[1] * v[1] + v[2] * v[2] + v[3] * v[3]);
        const float inv = 1.f / (nrm + 1e-8f);
        ushort4 u;
        u.x = f2h(v[0] * inv); u.y = f2h(v[1] * inv);
        u.z = f2h(v[2] * inv); u.w = f2h(v[3] * inv);
        *(ushort4*)&OutB[(size_t)token * 1024 + n] = u;
        if constexpr (EPI == 2) loss += fabsf(v[0] * inv);
      }
    }
    if constexpr (EPI == 2) {
#pragma unroll
      for (int off = 32; off > 0; off >>= 1) loss += __shfl_down(loss, off);
      if (lane == 0) lsum[wave] = loss;
      __syncthreads();
      if (tid == 0) {
        float t = 0.f;
#pragma unroll
        for (int w8 = 0; w8 < 8; w8++) t += lsum[w8];
        atomicAdd(OutF, t * (1.f / 8388608.f));
      }
    }
  } else {  // EPI == 3 : head
#pragma unroll
    for (int tn = 0; tn < 8; tn++) {
      const int n = nblock + wr * 128 + tn * 16 + quad * 4;
      if (n < 257) {
#pragma unroll
        for (int tm = 0; tm < 4; tm++) {
          const int token = mblock + wc * 64 + tm * 16 + l15;
          const f32x4 v = acc[tn][tm];
#pragma unroll
          for (int r = 0; r < 4; r++)
            if (n + r < 257) OutF[(size_t)token * 257 + n + r] = v[r];
        }
      }
    }
  }
}

// ---------------------------------------------------------------------------
extern "C" void kernel_launch(void* const* d_in, const int* in_sizes, int n_in,
                              void* d_out, int out_size, void* d_ws,
                              size_t ws_size, hipStream_t stream) {
  const int*   x    = (const int*)d_in[0];
  const float* emb  = (const float*)d_in[1];
  const float* we0  = (const float*)d_in[2];
  const float* we1  = (const float*)d_in[3];
  const float* we2  = (const float*)d_in[4];
  const float* we3  = (const float*)d_in[5];
  const float* we4  = (const float*)d_in[6];
  const float* we5  = (const float*)d_in[7];
  const float* we6  = (const float*)d_in[8];
  const float* we7  = (const float*)d_in[9];
  const float* wlay = (const float*)d_in[10];
  const float* wh   = (const float*)d_in[11];
  float* out = (float*)d_out;

  // workspace layout (~142 MiB)
  char* p = (char*)d_ws;
  auto alloc = [&](size_t bytes) {
    void* r = (void*)p;
    p += (bytes + 255) & ~(size_t)255;
    return r;
  };
  unsigned short* act0 = (unsigned short*)alloc(32768ull * 1024 * 2);
  unsigned short* act1 = (unsigned short*)alloc(32768ull * 1024 * 2);
  unsigned short* E4 = (unsigned short*)alloc(128 * 64 * 2);
  unsigned short* E5 = (unsigned short*)alloc(128 * 128 * 2);
  unsigned short* E6 = (unsigned short*)alloc(256 * 256 * 2);
  unsigned short* E7 = (unsigned short*)alloc(512 * 512 * 2);
  unsigned short* EL = (unsigned short*)alloc(6ull * 1024 * 1024 * 2);
  unsigned short* WH = (unsigned short*)alloc(384 * 1024 * 2);

  // zero the stability-loss slot (d_out is poisoned before every launch)
  hipMemsetAsync(out + 8421376, 0, 4, stream);

  // weight expansion (Hamilton blocks -> real fp16 matrices)
  expand_ham<<<dim3(8192 / 256), 256, 0, stream>>>(we4, E4, 16, 6, 128 * 64);
  expand_ham<<<dim3(16384 / 256), 256, 0, stream>>>(we5, E5, 32, 7, 128 * 128);
  expand_ham<<<dim3(65536 / 256), 256, 0, stream>>>(we6, E6, 64, 8, 256 * 256);
  expand_ham<<<dim3(262144 / 256), 256, 0, stream>>>(we7, E7, 128, 9,
                                                     512 * 512);
  for (int d = 0; d < 6; d++)
    expand_ham<<<dim3(1048576 / 256), 256, 0, stream>>>(
        wlay + (size_t)d * 262144, EL + (size_t)d * 1048576, 256, 10, 1048576);
  conv_head<<<dim3(384 * 1024 / 256), 256, 0, stream>>>(wh, WH);

  // embed + expansion steps 0..3 -> act0 [32768][64] fp16
  embed_expand<<<dim3(128), 256, 0, stream>>>(x, emb, we0, we1, we2, we3, act0);

  // expansion steps 4..7 as fused GEMMs (old 128x128 kernel)
  gemm_epi<0><<<dim3(1, 256), 256, 0, stream>>>(E4, act0, act1, nullptr, 64,
                                                64, 128);
  gemm_epi<0><<<dim3(1, 256), 256, 0, stream>>>(E5, act1, act0, nullptr, 128,
                                                128, 256);
  gemm_epi<0><<<dim3(2, 256), 256, 0, stream>>>(E6, act0, act1, nullptr, 256,
                                                256, 512);
  gemm_epi<0><<<dim3(4, 256), 256, 0, stream>>>(E7, act1, act0, nullptr, 512,
                                                512, 1024);

  // 6 quaternion-linear + normalize layers on the 256x256 scheduled kernel
  unsigned short* a = act0;
  unsigned short* b = act1;
  for (int d = 0; d < 5; d++) {
    gemm8p<1><<<dim3(4, 128), 512, 0, stream>>>(EL + (size_t)d * 1048576, a, b,
                                                nullptr, 1024, 1024);
    unsigned short* t = a; a = b; b = t;
  }
  gemm8p<2><<<dim3(4, 128), 512, 0, stream>>>(EL + 5ull * 1048576, a, b,
                                              out + 8421376, 1024, 1024);
  { unsigned short* t = a; a = b; b = t; }

  // head: logits = h @ w_head^T  (N padded 257 -> 384 in WH, tile-padded to
  // 512 via clamped W-row staging; masked stores n<257)
  gemm8p<3><<<dim3(2, 128), 512, 0, stream>>>(WH, a, nullptr, out, 1024, 384);
}